// Round 1
// baseline (793.125 us; speedup 1.0000x reference)
//
#include <hip/hip_runtime.h>

// Grid dims from the reference
#define BDIM 4
#define ZDIM 6
#define YDIM 200
#define XDIM 176
#define CDIM 64
#define KSLOTS (BDIM * ZDIM * YDIM * XDIM)  // 844800

// Monotonic float -> uint order encoding: preserves total order, so
// atomicMax on the encoded uint == float max. 0u is below every encoded
// real float (enc(-inf) = 0x007FFFFF), so memset-0 is the "empty" sentinel.
__device__ __forceinline__ unsigned ord_enc(float f) {
    unsigned u = __float_as_uint(f);
    return (u & 0x80000000u) ? ~u : (u | 0x80000000u);
}
__device__ __forceinline__ float ord_dec(unsigned u) {
    return (u & 0x80000000u) ? __uint_as_float(u & 0x7FFFFFFFu)
                             : __uint_as_float(~u);
}

__device__ __forceinline__ int voxel_key(const int4 c) {
    return ((c.x * ZDIM + c.y) * YDIM + c.z) * XDIM + c.w;
}

// One thread handles 4 channels of one point (float4 coalesced read).
__global__ void scatter_max_kernel(const float* __restrict__ feats,
                                   const int* __restrict__ coords,
                                   unsigned* __restrict__ out, int npts) {
    long long i = (long long)blockIdx.x * blockDim.x + threadIdx.x;
    long long total = (long long)npts * (CDIM / 4);
    if (i >= total) return;
    int pt = (int)(i >> 4);         // CDIM/4 == 16
    int c4 = (int)(i & 15);
    int4 cc = *reinterpret_cast<const int4*>(coords + (long long)pt * 4);
    int key = voxel_key(cc);
    float4 f = *reinterpret_cast<const float4*>(feats + (long long)pt * CDIM + c4 * 4);
    unsigned* dst = out + (long long)key * CDIM + c4 * 4;
    atomicMax(dst + 0, ord_enc(f.x));
    atomicMax(dst + 1, ord_enc(f.y));
    atomicMax(dst + 2, ord_enc(f.z));
    atomicMax(dst + 3, ord_enc(f.w));
}

// In-place: encoded uint -> float; 0u (never written) -> 0.0f
__global__ void decode_kernel(unsigned* __restrict__ buf, long long n4) {
    long long i = (long long)blockIdx.x * blockDim.x + threadIdx.x;
    if (i >= n4) return;
    uint4 u = reinterpret_cast<const uint4*>(buf)[i];
    float4 f;
    f.x = (u.x == 0u) ? 0.0f : ord_dec(u.x);
    f.y = (u.y == 0u) ? 0.0f : ord_dec(u.y);
    f.z = (u.z == 0u) ? 0.0f : ord_dec(u.z);
    f.w = (u.w == 0u) ? 0.0f : ord_dec(u.w);
    reinterpret_cast<float4*>(buf)[i] = f;
}

__global__ void scatter_add_kernel(const float* __restrict__ feats,
                                   const int* __restrict__ coords,
                                   float* __restrict__ out, int npts) {
    long long i = (long long)blockIdx.x * blockDim.x + threadIdx.x;
    long long total = (long long)npts * (CDIM / 4);
    if (i >= total) return;
    int pt = (int)(i >> 4);
    int c4 = (int)(i & 15);
    int4 cc = *reinterpret_cast<const int4*>(coords + (long long)pt * 4);
    int key = voxel_key(cc);
    float4 f = *reinterpret_cast<const float4*>(feats + (long long)pt * CDIM + c4 * 4);
    float* dst = out + (long long)key * CDIM + c4 * 4;
    atomicAdd(dst + 0, f.x);
    atomicAdd(dst + 1, f.y);
    atomicAdd(dst + 2, f.z);
    atomicAdd(dst + 3, f.w);
}

extern "C" void kernel_launch(void* const* d_in, const int* in_sizes, int n_in,
                              void* d_out, int out_size, void* d_ws, size_t ws_size,
                              hipStream_t stream) {
    const float* feats1 = (const float*)d_in[0];
    const int*   coords1 = (const int*)d_in[1];
    const float* feats2 = (const float*)d_in[2];
    const int*   coords2 = (const int*)d_in[3];
    float* out = (float*)d_out;

    const int n1 = in_sizes[1] / 4;   // coords1 is [N1,4]
    const int n2 = in_sizes[3] / 4;   // coords2 is [N2,4]
    const long long kc = (long long)KSLOTS * CDIM;  // == out_size

    // Pass 1: zero output (0u == empty sentinel in encoded space)
    hipMemsetAsync(d_out, 0, kc * sizeof(float), stream);

    // Pass 2: scatter-max feats2 (encoded uints)
    {
        long long total = (long long)n2 * (CDIM / 4);
        int blocks = (int)((total + 255) / 256);
        scatter_max_kernel<<<blocks, 256, 0, stream>>>(feats2, coords2,
                                                       (unsigned*)out, n2);
    }
    // Pass 3: decode in place (empty -> 0.0f)
    {
        long long n4 = kc / 4;
        int blocks = (int)((n4 + 255) / 256);
        decode_kernel<<<blocks, 256, 0, stream>>>((unsigned*)out, n4);
    }
    // Pass 4: scatter-add feats1
    {
        long long total = (long long)n1 * (CDIM / 4);
        int blocks = (int)((total + 255) / 256);
        scatter_add_kernel<<<blocks, 256, 0, stream>>>(feats1, coords1, out, n1);
    }
}

// Round 2
// 331.601 us; speedup vs baseline: 2.3918x; 2.3918x over previous
//
#include <hip/hip_runtime.h>
#include <float.h>

// Grid dims from the reference
#define BDIM 4
#define ZDIM 6
#define YDIM 200
#define XDIM 176
#define CDIM 64
#define KSLOTS (BDIM * ZDIM * YDIM * XDIM)  // 844800
#define SCAN_W 1024                          // elems per scan block
#define NSCAN (KSLOTS / SCAN_W)              // 825 (exact: 844800 = 825*1024)

__device__ __forceinline__ int voxel_key4(const int4 c) {
    return ((c.x * ZDIM + c.y) * YDIM + c.z) * XDIM + c.w;
}

// ---------------- CSR build ----------------

__global__ void hist_kernel(const int* __restrict__ coords, int* __restrict__ cnt,
                            int npts) {
    int i = blockIdx.x * blockDim.x + threadIdx.x;
    if (i >= npts) return;
    int4 cc = *reinterpret_cast<const int4*>(coords + (long long)i * 4);
    atomicAdd(&cnt[voxel_key4(cc)], 1);
}

// Level-1 scan: each 1024-thread block scans 1024 counters; writes per-elem
// EXCLUSIVE prefix into pos[], block total into bsum[block].
__global__ void scan1_kernel(const int* __restrict__ cnt, int* __restrict__ pos,
                             int* __restrict__ bsum) {
    __shared__ int s[SCAN_W];
    int t = threadIdx.x;
    int g = blockIdx.x * SCAN_W + t;
    s[t] = cnt[g];
    __syncthreads();
    #pragma unroll
    for (int off = 1; off < SCAN_W; off <<= 1) {
        int v = (t >= off) ? s[t - off] : 0;
        __syncthreads();
        s[t] += v;
        __syncthreads();
    }
    pos[g] = (t > 0) ? s[t - 1] : 0;
    if (t == SCAN_W - 1) bsum[blockIdx.x] = s[t];
}

// Level-2: one block scans the block sums (exclusive, in place).
__global__ void scan2_kernel(int* __restrict__ bsum, int nblocks) {
    __shared__ int s[SCAN_W];
    int t = threadIdx.x;
    s[t] = (t < nblocks) ? bsum[t] : 0;
    __syncthreads();
    #pragma unroll
    for (int off = 1; off < SCAN_W; off <<= 1) {
        int v = (t >= off) ? s[t - off] : 0;
        __syncthreads();
        s[t] += v;
        __syncthreads();
    }
    bsum[t] = (t > 0) ? s[t - 1] : 0;
}

// Level-3: add block offsets.
__global__ void scan3_kernel(int* __restrict__ pos, const int* __restrict__ bsum) {
    int g = blockIdx.x * SCAN_W + threadIdx.x;
    pos[g] += bsum[blockIdx.x];
}

// Scatter point indices into CSR slots. pos[] acts as cursor; after this
// kernel pos[key] == exclusive END of the run (begin = end - cnt[key]).
__global__ void scatter_idx_kernel(const int* __restrict__ coords,
                                   int* __restrict__ pos, int* __restrict__ idx,
                                   int npts) {
    int i = blockIdx.x * blockDim.x + threadIdx.x;
    if (i >= npts) return;
    int4 cc = *reinterpret_cast<const int4*>(coords + (long long)i * 4);
    int slot = atomicAdd(&pos[voxel_key4(cc)], 1);
    idx[slot] = i;
}

// ---------------- fused output pass ----------------
// One thread per (voxel, channel-quad): max over run2 (or 0 if empty),
// sum over run1, write float4 exactly once. No atomics, no memset.
__global__ void fuse_kernel(const float* __restrict__ f1, const int* __restrict__ idx1,
                            const int* __restrict__ cnt1, const int* __restrict__ end1,
                            const float* __restrict__ f2, const int* __restrict__ idx2,
                            const int* __restrict__ cnt2, const int* __restrict__ end2,
                            float* __restrict__ out) {
    long long tid = (long long)blockIdx.x * blockDim.x + threadIdx.x;
    if (tid >= (long long)KSLOTS * (CDIM / 4)) return;
    int vox = (int)(tid >> 4);
    int c4 = (int)(tid & 15);

    // max-pool over run2
    int e2 = end2[vox], n2 = cnt2[vox], b2 = e2 - n2;
    float4 m = make_float4(-FLT_MAX, -FLT_MAX, -FLT_MAX, -FLT_MAX);
    for (int j = b2; j < e2; ++j) {
        int p = idx2[j];
        float4 f = *reinterpret_cast<const float4*>(f2 + (long long)p * CDIM + c4 * 4);
        m.x = fmaxf(m.x, f.x); m.y = fmaxf(m.y, f.y);
        m.z = fmaxf(m.z, f.z); m.w = fmaxf(m.w, f.w);
    }
    if (n2 == 0) m = make_float4(0.f, 0.f, 0.f, 0.f);

    // sum over run1
    int e1 = end1[vox], n1 = cnt1[vox], b1 = e1 - n1;
    float4 s = make_float4(0.f, 0.f, 0.f, 0.f);
    for (int j = b1; j < e1; ++j) {
        int p = idx1[j];
        float4 f = *reinterpret_cast<const float4*>(f1 + (long long)p * CDIM + c4 * 4);
        s.x += f.x; s.y += f.y; s.z += f.z; s.w += f.w;
    }

    float4 o = make_float4(s.x + m.x, s.y + m.y, s.z + m.z, s.w + m.w);
    *reinterpret_cast<float4*>(out + (long long)vox * CDIM + c4 * 4) = o;
}

// ---------------- fallback (round-1 atomic path, used only if ws too small) ----

__device__ __forceinline__ unsigned ord_enc(float f) {
    unsigned u = __float_as_uint(f);
    return (u & 0x80000000u) ? ~u : (u | 0x80000000u);
}
__device__ __forceinline__ float ord_dec(unsigned u) {
    return (u & 0x80000000u) ? __uint_as_float(u & 0x7FFFFFFFu)
                             : __uint_as_float(~u);
}

__global__ void fb_scatter_max(const float* __restrict__ feats, const int* __restrict__ coords,
                               unsigned* __restrict__ out, int npts) {
    long long i = (long long)blockIdx.x * blockDim.x + threadIdx.x;
    if (i >= (long long)npts * (CDIM / 4)) return;
    int pt = (int)(i >> 4), c4 = (int)(i & 15);
    int4 cc = *reinterpret_cast<const int4*>(coords + (long long)pt * 4);
    int key = voxel_key4(cc);
    float4 f = *reinterpret_cast<const float4*>(feats + (long long)pt * CDIM + c4 * 4);
    unsigned* dst = out + (long long)key * CDIM + c4 * 4;
    atomicMax(dst + 0, ord_enc(f.x));
    atomicMax(dst + 1, ord_enc(f.y));
    atomicMax(dst + 2, ord_enc(f.z));
    atomicMax(dst + 3, ord_enc(f.w));
}
__global__ void fb_decode(unsigned* __restrict__ buf, long long n4) {
    long long i = (long long)blockIdx.x * blockDim.x + threadIdx.x;
    if (i >= n4) return;
    uint4 u = reinterpret_cast<const uint4*>(buf)[i];
    float4 f;
    f.x = (u.x == 0u) ? 0.f : ord_dec(u.x);
    f.y = (u.y == 0u) ? 0.f : ord_dec(u.y);
    f.z = (u.z == 0u) ? 0.f : ord_dec(u.z);
    f.w = (u.w == 0u) ? 0.f : ord_dec(u.w);
    reinterpret_cast<float4*>(buf)[i] = f;
}
__global__ void fb_scatter_add(const float* __restrict__ feats, const int* __restrict__ coords,
                               float* __restrict__ out, int npts) {
    long long i = (long long)blockIdx.x * blockDim.x + threadIdx.x;
    if (i >= (long long)npts * (CDIM / 4)) return;
    int pt = (int)(i >> 4), c4 = (int)(i & 15);
    int4 cc = *reinterpret_cast<const int4*>(coords + (long long)pt * 4);
    int key = voxel_key4(cc);
    float4 f = *reinterpret_cast<const float4*>(feats + (long long)pt * CDIM + c4 * 4);
    float* dst = out + (long long)key * CDIM + c4 * 4;
    atomicAdd(dst + 0, f.x); atomicAdd(dst + 1, f.y);
    atomicAdd(dst + 2, f.z); atomicAdd(dst + 3, f.w);
}

extern "C" void kernel_launch(void* const* d_in, const int* in_sizes, int n_in,
                              void* d_out, int out_size, void* d_ws, size_t ws_size,
                              hipStream_t stream) {
    const float* feats1 = (const float*)d_in[0];
    const int*   coords1 = (const int*)d_in[1];
    const float* feats2 = (const float*)d_in[2];
    const int*   coords2 = (const int*)d_in[3];
    float* out = (float*)d_out;

    const int n1 = in_sizes[1] / 4;
    const int n2 = in_sizes[3] / 4;
    const long long kc = (long long)KSLOTS * CDIM;

    const size_t needed = ((size_t)4 * KSLOTS + n1 + n2 + 2 * SCAN_W) * sizeof(int);
    if (ws_size < needed) {
        // fallback: atomic path
        hipMemsetAsync(d_out, 0, kc * sizeof(float), stream);
        long long t2 = (long long)n2 * (CDIM / 4);
        fb_scatter_max<<<(int)((t2 + 255) / 256), 256, 0, stream>>>(feats2, coords2,
                                                                    (unsigned*)out, n2);
        long long q = kc / 4;
        fb_decode<<<(int)((q + 255) / 256), 256, 0, stream>>>((unsigned*)out, q);
        long long t1 = (long long)n1 * (CDIM / 4);
        fb_scatter_add<<<(int)((t1 + 255) / 256), 256, 0, stream>>>(feats1, coords1, out, n1);
        return;
    }

    int* cnt1 = (int*)d_ws;
    int* cnt2 = cnt1 + KSLOTS;
    int* pos1 = cnt2 + KSLOTS;
    int* pos2 = pos1 + KSLOTS;
    int* idx1 = pos2 + KSLOTS;
    int* idx2 = idx1 + n1;
    int* bsum1 = idx2 + n2;
    int* bsum2 = bsum1 + SCAN_W;

    // zero both count arrays (contiguous)
    hipMemsetAsync(cnt1, 0, (size_t)2 * KSLOTS * sizeof(int), stream);

    hist_kernel<<<(n1 + 255) / 256, 256, 0, stream>>>(coords1, cnt1, n1);
    hist_kernel<<<(n2 + 255) / 256, 256, 0, stream>>>(coords2, cnt2, n2);

    scan1_kernel<<<NSCAN, SCAN_W, 0, stream>>>(cnt1, pos1, bsum1);
    scan1_kernel<<<NSCAN, SCAN_W, 0, stream>>>(cnt2, pos2, bsum2);
    scan2_kernel<<<1, SCAN_W, 0, stream>>>(bsum1, NSCAN);
    scan2_kernel<<<1, SCAN_W, 0, stream>>>(bsum2, NSCAN);
    scan3_kernel<<<NSCAN, SCAN_W, 0, stream>>>(pos1, bsum1);
    scan3_kernel<<<NSCAN, SCAN_W, 0, stream>>>(pos2, bsum2);

    scatter_idx_kernel<<<(n1 + 255) / 256, 256, 0, stream>>>(coords1, pos1, idx1, n1);
    scatter_idx_kernel<<<(n2 + 255) / 256, 256, 0, stream>>>(coords2, pos2, idx2, n2);

    long long total = (long long)KSLOTS * (CDIM / 4);
    fuse_kernel<<<(int)((total + 255) / 256), 256, 0, stream>>>(
        feats1, idx1, cnt1, pos1, feats2, idx2, cnt2, pos2, out);
}

// Round 3
// 270.820 us; speedup vs baseline: 2.9286x; 1.2244x over previous
//
#include <hip/hip_runtime.h>
#include <float.h>

// Grid dims from the reference
#define BDIM 4
#define ZDIM 6
#define YDIM 200
#define XDIM 176
#define CDIM 64
#define KSLOTS (BDIM * ZDIM * YDIM * XDIM)  // 844800
#define SCAN_W 1024
#define NSCAN (KSLOTS / SCAN_W)              // 825 (exact)

typedef float f32x4 __attribute__((ext_vector_type(4)));

__device__ __forceinline__ int voxel_key4(const int4 c) {
    return ((c.x * ZDIM + c.y) * YDIM + c.z) * XDIM + c.w;
}

// ---------------- CSR build (fused launches) ----------------

// One kernel histograms both coord arrays.
__global__ void hist2_kernel(const int* __restrict__ c1, int n1, int* __restrict__ cnt1,
                             const int* __restrict__ c2, int n2, int* __restrict__ cnt2) {
    int i = blockIdx.x * blockDim.x + threadIdx.x;
    if (i < n1) {
        int4 cc = *reinterpret_cast<const int4*>(c1 + (long long)i * 4);
        atomicAdd(&cnt1[voxel_key4(cc)], 1);
    } else if (i < n1 + n2) {
        int j = i - n1;
        int4 cc = *reinterpret_cast<const int4*>(c2 + (long long)j * 4);
        atomicAdd(&cnt2[voxel_key4(cc)], 1);
    }
}

// Level-1 scan over both count arrays (blockIdx selects array).
__global__ void scan1_kernel(const int* __restrict__ cntA, int* __restrict__ posA,
                             int* __restrict__ bsumA,
                             const int* __restrict__ cntB, int* __restrict__ posB,
                             int* __restrict__ bsumB) {
    __shared__ int s[SCAN_W];
    const int* cnt; int* pos; int* bsum; int blk;
    if (blockIdx.x < NSCAN) { cnt = cntA; pos = posA; bsum = bsumA; blk = blockIdx.x; }
    else                    { cnt = cntB; pos = posB; bsum = bsumB; blk = blockIdx.x - NSCAN; }
    int t = threadIdx.x;
    int g = blk * SCAN_W + t;
    s[t] = cnt[g];
    __syncthreads();
    #pragma unroll
    for (int off = 1; off < SCAN_W; off <<= 1) {
        int v = (t >= off) ? s[t - off] : 0;
        __syncthreads();
        s[t] += v;
        __syncthreads();
    }
    pos[g] = (t > 0) ? s[t - 1] : 0;
    if (t == SCAN_W - 1) bsum[blk] = s[t];
}

// Level-2: block 0 scans bsumA, block 1 scans bsumB (exclusive, in place).
__global__ void scan2_kernel(int* __restrict__ bsumA, int* __restrict__ bsumB) {
    __shared__ int s[SCAN_W];
    int* bsum = (blockIdx.x == 0) ? bsumA : bsumB;
    int t = threadIdx.x;
    s[t] = (t < NSCAN) ? bsum[t] : 0;
    __syncthreads();
    #pragma unroll
    for (int off = 1; off < SCAN_W; off <<= 1) {
        int v = (t >= off) ? s[t - off] : 0;
        __syncthreads();
        s[t] += v;
        __syncthreads();
    }
    bsum[t] = (t > 0) ? s[t - 1] : 0;
}

// Level-3: add block offsets; write rowptr AND cursor copy (cursor reuses cnt buf).
__global__ void scan3_kernel(int* __restrict__ posA, int* __restrict__ curA,
                             const int* __restrict__ bsumA,
                             int* __restrict__ posB, int* __restrict__ curB,
                             const int* __restrict__ bsumB) {
    int* pos; int* cur; const int* bsum; int blk;
    if (blockIdx.x < NSCAN) { pos = posA; cur = curA; bsum = bsumA; blk = blockIdx.x; }
    else                    { pos = posB; cur = curB; bsum = bsumB; blk = blockIdx.x - NSCAN; }
    int g = blk * SCAN_W + threadIdx.x;
    int v = pos[g] + bsum[blk];
    pos[g] = v;
    cur[g] = v;
}

// Scatter both point sets into CSR slots via cursors.
__global__ void scatter2_kernel(const int* __restrict__ c1, int n1,
                                int* __restrict__ cur1, int* __restrict__ idx1,
                                const int* __restrict__ c2, int n2,
                                int* __restrict__ cur2, int* __restrict__ idx2) {
    int i = blockIdx.x * blockDim.x + threadIdx.x;
    if (i < n1) {
        int4 cc = *reinterpret_cast<const int4*>(c1 + (long long)i * 4);
        int slot = atomicAdd(&cur1[voxel_key4(cc)], 1);
        idx1[slot] = i;
    } else if (i < n1 + n2) {
        int j = i - n1;
        int4 cc = *reinterpret_cast<const int4*>(c2 + (long long)j * 4);
        int slot = atomicAdd(&cur2[voxel_key4(cc)], 1);
        idx2[slot] = j;
    }
}

// ---------------- fused output pass ----------------

__device__ __forceinline__ float4 fmax4(float4 a, float4 b) {
    return make_float4(fmaxf(a.x, b.x), fmaxf(a.y, b.y), fmaxf(a.z, b.z), fmaxf(a.w, b.w));
}

__global__ __launch_bounds__(256) void fuse_kernel(
        const float* __restrict__ f1, const int* __restrict__ idx1,
        const int* __restrict__ pos1, int n1,
        const float* __restrict__ f2, const int* __restrict__ idx2,
        const int* __restrict__ pos2, int n2,
        float* __restrict__ out) {
    long long tid = (long long)blockIdx.x * blockDim.x + threadIdx.x;
    int vox = (int)(tid >> 4);
    int c4 = (int)(tid & 15);
    bool last = (vox == KSLOTS - 1);
    int b2 = pos2[vox];
    int e2 = last ? n2 : pos2[vox + 1];
    int b1 = pos1[vox];
    int e1 = last ? n1 : pos1[vox + 1];

    // ---- max-pool over run2, 4/2/1-way MLP batching ----
    float4 m = make_float4(-FLT_MAX, -FLT_MAX, -FLT_MAX, -FLT_MAX);
    int j = b2;
    while (e2 - j >= 4) {
        int p0 = idx2[j], p1 = idx2[j + 1], p2 = idx2[j + 2], p3 = idx2[j + 3];
        float4 fa = *reinterpret_cast<const float4*>(f2 + (long long)p0 * CDIM + c4 * 4);
        float4 fb = *reinterpret_cast<const float4*>(f2 + (long long)p1 * CDIM + c4 * 4);
        float4 fc = *reinterpret_cast<const float4*>(f2 + (long long)p2 * CDIM + c4 * 4);
        float4 fd = *reinterpret_cast<const float4*>(f2 + (long long)p3 * CDIM + c4 * 4);
        m = fmax4(m, fmax4(fmax4(fa, fb), fmax4(fc, fd)));
        j += 4;
    }
    if (e2 - j >= 2) {
        int p0 = idx2[j], p1 = idx2[j + 1];
        float4 fa = *reinterpret_cast<const float4*>(f2 + (long long)p0 * CDIM + c4 * 4);
        float4 fb = *reinterpret_cast<const float4*>(f2 + (long long)p1 * CDIM + c4 * 4);
        m = fmax4(m, fmax4(fa, fb));
        j += 2;
    }
    if (j < e2) {
        int p0 = idx2[j];
        float4 fa = *reinterpret_cast<const float4*>(f2 + (long long)p0 * CDIM + c4 * 4);
        m = fmax4(m, fa);
    }
    if (b2 == e2) m = make_float4(0.f, 0.f, 0.f, 0.f);

    // ---- sum over run1, 2/1-way batching ----
    float4 s = make_float4(0.f, 0.f, 0.f, 0.f);
    j = b1;
    while (e1 - j >= 2) {
        int p0 = idx1[j], p1 = idx1[j + 1];
        float4 fa = *reinterpret_cast<const float4*>(f1 + (long long)p0 * CDIM + c4 * 4);
        float4 fb = *reinterpret_cast<const float4*>(f1 + (long long)p1 * CDIM + c4 * 4);
        s.x += fa.x + fb.x; s.y += fa.y + fb.y;
        s.z += fa.z + fb.z; s.w += fa.w + fb.w;
        j += 2;
    }
    if (j < e1) {
        int p0 = idx1[j];
        float4 fa = *reinterpret_cast<const float4*>(f1 + (long long)p0 * CDIM + c4 * 4);
        s.x += fa.x; s.y += fa.y; s.z += fa.z; s.w += fa.w;
    }

    f32x4 o = { s.x + m.x, s.y + m.y, s.z + m.z, s.w + m.w };
    __builtin_nontemporal_store(o,
        reinterpret_cast<f32x4*>(out + (long long)vox * CDIM + c4 * 4));
}

// ---------------- fallback (atomic path, used only if ws too small) ----------

__device__ __forceinline__ unsigned ord_enc(float f) {
    unsigned u = __float_as_uint(f);
    return (u & 0x80000000u) ? ~u : (u | 0x80000000u);
}
__device__ __forceinline__ float ord_dec(unsigned u) {
    return (u & 0x80000000u) ? __uint_as_float(u & 0x7FFFFFFFu)
                             : __uint_as_float(~u);
}
__global__ void fb_scatter_max(const float* __restrict__ feats, const int* __restrict__ coords,
                               unsigned* __restrict__ out, int npts) {
    long long i = (long long)blockIdx.x * blockDim.x + threadIdx.x;
    if (i >= (long long)npts * (CDIM / 4)) return;
    int pt = (int)(i >> 4), c4 = (int)(i & 15);
    int4 cc = *reinterpret_cast<const int4*>(coords + (long long)pt * 4);
    int key = voxel_key4(cc);
    float4 f = *reinterpret_cast<const float4*>(feats + (long long)pt * CDIM + c4 * 4);
    unsigned* dst = out + (long long)key * CDIM + c4 * 4;
    atomicMax(dst + 0, ord_enc(f.x));
    atomicMax(dst + 1, ord_enc(f.y));
    atomicMax(dst + 2, ord_enc(f.z));
    atomicMax(dst + 3, ord_enc(f.w));
}
__global__ void fb_decode(unsigned* __restrict__ buf, long long n4) {
    long long i = (long long)blockIdx.x * blockDim.x + threadIdx.x;
    if (i >= n4) return;
    uint4 u = reinterpret_cast<const uint4*>(buf)[i];
    float4 f;
    f.x = (u.x == 0u) ? 0.f : ord_dec(u.x);
    f.y = (u.y == 0u) ? 0.f : ord_dec(u.y);
    f.z = (u.z == 0u) ? 0.f : ord_dec(u.z);
    f.w = (u.w == 0u) ? 0.f : ord_dec(u.w);
    reinterpret_cast<float4*>(buf)[i] = f;
}
__global__ void fb_scatter_add(const float* __restrict__ feats, const int* __restrict__ coords,
                               float* __restrict__ out, int npts) {
    long long i = (long long)blockIdx.x * blockDim.x + threadIdx.x;
    if (i >= (long long)npts * (CDIM / 4)) return;
    int pt = (int)(i >> 4), c4 = (int)(i & 15);
    int4 cc = *reinterpret_cast<const int4*>(coords + (long long)pt * 4);
    int key = voxel_key4(cc);
    float4 f = *reinterpret_cast<const float4*>(feats + (long long)pt * CDIM + c4 * 4);
    float* dst = out + (long long)key * CDIM + c4 * 4;
    atomicAdd(dst + 0, f.x); atomicAdd(dst + 1, f.y);
    atomicAdd(dst + 2, f.z); atomicAdd(dst + 3, f.w);
}

extern "C" void kernel_launch(void* const* d_in, const int* in_sizes, int n_in,
                              void* d_out, int out_size, void* d_ws, size_t ws_size,
                              hipStream_t stream) {
    const float* feats1 = (const float*)d_in[0];
    const int*   coords1 = (const int*)d_in[1];
    const float* feats2 = (const float*)d_in[2];
    const int*   coords2 = (const int*)d_in[3];
    float* out = (float*)d_out;

    const int n1 = in_sizes[1] / 4;
    const int n2 = in_sizes[3] / 4;
    const long long kc = (long long)KSLOTS * CDIM;

    const size_t needed = ((size_t)4 * KSLOTS + n1 + n2 + 2 * SCAN_W) * sizeof(int);
    if (ws_size < needed) {
        hipMemsetAsync(d_out, 0, kc * sizeof(float), stream);
        long long t2 = (long long)n2 * (CDIM / 4);
        fb_scatter_max<<<(int)((t2 + 255) / 256), 256, 0, stream>>>(feats2, coords2,
                                                                    (unsigned*)out, n2);
        long long q = kc / 4;
        fb_decode<<<(int)((q + 255) / 256), 256, 0, stream>>>((unsigned*)out, q);
        long long t1 = (long long)n1 * (CDIM / 4);
        fb_scatter_add<<<(int)((t1 + 255) / 256), 256, 0, stream>>>(feats1, coords1, out, n1);
        return;
    }

    // ws layout: cnt1|cnt2 (double as cursors) | pos1|pos2 | idx1|idx2 | bsum1|bsum2
    int* cnt1 = (int*)d_ws;
    int* cnt2 = cnt1 + KSLOTS;
    int* pos1 = cnt2 + KSLOTS;
    int* pos2 = pos1 + KSLOTS;
    int* idx1 = pos2 + KSLOTS;
    int* idx2 = idx1 + n1;
    int* bsum1 = idx2 + n2;
    int* bsum2 = bsum1 + SCAN_W;

    hipMemsetAsync(cnt1, 0, (size_t)2 * KSLOTS * sizeof(int), stream);

    int nb12 = (n1 + n2 + 255) / 256;
    hist2_kernel<<<nb12, 256, 0, stream>>>(coords1, n1, cnt1, coords2, n2, cnt2);

    scan1_kernel<<<2 * NSCAN, SCAN_W, 0, stream>>>(cnt1, pos1, bsum1, cnt2, pos2, bsum2);
    scan2_kernel<<<2, SCAN_W, 0, stream>>>(bsum1, bsum2);
    scan3_kernel<<<2 * NSCAN, SCAN_W, 0, stream>>>(pos1, cnt1, bsum1, pos2, cnt2, bsum2);

    scatter2_kernel<<<nb12, 256, 0, stream>>>(coords1, n1, cnt1, idx1,
                                              coords2, n2, cnt2, idx2);

    long long total = (long long)KSLOTS * (CDIM / 4);
    fuse_kernel<<<(int)(total / 256), 256, 0, stream>>>(
        feats1, idx1, pos1, n1, feats2, idx2, pos2, n2, out);
}